// Round 6
// baseline (128.014 us; speedup 1.0000x reference)
//
#include <hip/hip_runtime.h>
#include <hip/hip_bf16.h>

// Dilated-mask attention, B=2 H=16 S=2048 D=64, dilation=2.
// mask[i,j]=1 iff same parity; masked scores exactly 0 -> flash attn over
// same-parity keys with fixed m=0, Z = l + 1024, out += Vsum_otherparity.
//
// R12: LDS-free main loop. R11 PMC accounting: DS pipe ~75% busy (49k cy
// frag reads + 12k staging writes + 16.6k conflict cy per CU) -> LDS-bound.
// Fix: convf writes K/V as FRAGMENT-ORDERED bf16 arrays (exact per-lane data
// of the verified 16x16 fragments); attn4 loads frags with coalesced
// global_load_dwordx4/x2 from L1/L2 (16 MB, L2-resident; 4 waves/block read
// identical addresses -> L1 hits; XCD-clustered block swizzle keeps each
// XCD's 8 bp slices ~2MB in its private L2). No ds_read, no ds_write, no
// __syncthreads in the main loop; 2-deep register double-buffer with static
// A/B sets. Compute = R7's verified dual-qf 32q/wave pipeline, numerics
// unchanged. Opp-parity Vsum partials (vpp) folded into convf; fallback =
// verified R9 path.

#define B_   2
#define H_   16
#define S_   2048
#define D_   64
#define SP_  1024
#define BQ   128        // attn4: 4 waves x 32 queries
#define FBQ  64         // fallback (R9) queries per block
#define BK   64
#define NKT  (SP_ / BK)

// Q pre-scale: 1/sqrt(64) * log2(e)  ->  p = exp2(QK') = exp(QK/8)
#define QSCALE 0.180336884f

#if __has_builtin(__builtin_amdgcn_exp2f)
#define EXP2(x) __builtin_amdgcn_exp2f(x)
#else
#define EXP2(x) exp2f(x)
#endif

typedef __bf16 bf16x8 __attribute__((ext_vector_type(8)));
typedef __bf16 bf16x4 __attribute__((ext_vector_type(4)));
typedef float  f32x4  __attribute__((ext_vector_type(4)));
typedef short  s16x4  __attribute__((ext_vector_type(4)));

static __device__ __forceinline__ f32x4 mfma16(bf16x4 a, bf16x4 b, f32x4 c) {
    return __builtin_amdgcn_mfma_f32_16x16x16bf16_1k(
        __builtin_bit_cast(s16x4, a), __builtin_bit_cast(s16x4, b), c, 0, 0, 0);
}

// XOR swizzle used only by the fallback path (R9 layout).
#define KSW(r, c8) ((((c8) ^ ((r) & 7)) << 3))

// ---------------------------------------------------------------------------
// convf: fragment-ordered conversion.
//  Kf[((bp*16+kt)*8 + (ks*4+kt4))*512 + lane*8 + j] =
//      bf16( K[bh][par+2*(kt*64+kt4*16+(lane&15))][(ks*4+(lane>>4))*8 + j] )
//  Vf[((bp*16+kt)*16 + (kt4*4+dt))*256 + lane*4 + j] =
//      bf16( V[bh][par+2*(kt*64+kt4*16+(lane>>4)*4+j)][dt*16+(lane&15)] )
//  vpp[bp][kt][d] = sum over the tile's 64 parity-local keys of fp32 V[..][d]
// grid (64 bp, 16 kt), 256 threads (wave w handles kt4=w for V, frags 2w,2w+1 for K).
// ---------------------------------------------------------------------------
__global__ __launch_bounds__(256) void convf_kernel(const float* __restrict__ K,
                                                    const float* __restrict__ V,
                                                    __bf16* __restrict__ Kf,
                                                    __bf16* __restrict__ Vf,
                                                    float* __restrict__ vpp) {
    const int bp  = blockIdx.x;          // bh*2 + par
    const int kt  = blockIdx.y;
    const int bh  = bp >> 1;
    const int par = bp & 1;
    const int tid  = threadIdx.x;
    const int lane = tid & 63;
    const int w    = tid >> 6;
    const int l15  = lane & 15;
    const int quad = lane >> 4;
    const float* Kb = K + (size_t)bh * S_ * D_;
    const float* Vb = V + (size_t)bh * S_ * D_;

    // ---- K fragments: f = w*2 + i ----
    #pragma unroll
    for (int i = 0; i < 2; ++i) {
        const int f   = w * 2 + i;
        const int ks  = f >> 2;
        const int kt4 = f & 3;
        const int key = kt * 64 + kt4 * 16 + l15;
        const float* src = Kb + (size_t)(par + 2 * key) * D_ + (ks * 4 + quad) * 8;
        const float4 a = *(const float4*)src;
        const float4 b = *(const float4*)(src + 4);
        bf16x8 wv;
        wv[0] = (__bf16)a.x; wv[1] = (__bf16)a.y;
        wv[2] = (__bf16)a.z; wv[3] = (__bf16)a.w;
        wv[4] = (__bf16)b.x; wv[5] = (__bf16)b.y;
        wv[6] = (__bf16)b.z; wv[7] = (__bf16)b.w;
        *(bf16x8*)&Kf[(((size_t)bp * NKT + kt) * 8 + f) * 512 + lane * 8] = wv;
    }

    // ---- V fragments: kt4 = w, g = w*4 + dt; + fp32 column partials ----
    float ps[4];
    #pragma unroll
    for (int dt = 0; dt < 4; ++dt) {
        const int d = dt * 16 + l15;
        bf16x4 vv;
        float s = 0.f;
        #pragma unroll
        for (int j = 0; j < 4; ++j) {
            const int key = kt * 64 + w * 16 + quad * 4 + j;
            const float x = Vb[(size_t)(par + 2 * key) * D_ + d];
            vv[j] = (__bf16)x;
            s += x;
        }
        ps[dt] = s;
        *(bf16x4*)&Vf[(((size_t)bp * NKT + kt) * 16 + (w * 4 + dt)) * 256 + lane * 4] = vv;
    }

    // reduce over quads (lanes sharing l15), then over waves via LDS
    __shared__ float red[4][4][16];
    #pragma unroll
    for (int dt = 0; dt < 4; ++dt) {
        float s = ps[dt];
        s += __shfl_xor(s, 16);
        s += __shfl_xor(s, 32);
        if (lane < 16) red[w][dt][l15] = s;
    }
    __syncthreads();
    if (tid < 64) {
        const int dt = tid >> 4, p = tid & 15;
        vpp[((size_t)bp * NKT + kt) * 64 + tid] =
            (red[0][dt][p] + red[1][dt][p]) + (red[2][dt][p] + red[3][dt][p]);
    }
}

// ---------------------------------------------------------------------------
// attn4: no-LDS main loop, no barriers. 4 waves x 32 queries (dual-qf,
// R7-verified compute). Fragments loaded coalesced from Kf/Vf.
// ---------------------------------------------------------------------------
__global__ __launch_bounds__(256, 2) void attn4_kernel(const float* __restrict__ Q,
                                                       const __bf16* __restrict__ Kf,
                                                       const __bf16* __restrict__ Vf,
                                                       const float* __restrict__ vpp,
                                                       float* __restrict__ out) {
    // XCD-clustering decode (bijective, 512 = 8*64): blocks sharing one bp
    // slice land on one XCD -> its 2MB of Kf/Vf stays in that XCD's L2.
    const int h  = blockIdx.x;
    const int L  = (h & 7) * 64 + (h >> 3);
    const int qt  = L & 7;
    const int par = (L >> 3) & 1;
    const int bh  = L >> 4;
    const int bp  = bh * 2 + par;
    const int tid  = threadIdx.x;
    const int lane = tid & 63;
    const int wave = tid >> 6;       // wave owns queries [32w, 32w+32)
    const int l15  = lane & 15;
    const int quad = lane >> 4;

    const size_t base = (size_t)bh * S_ * D_;

    // ---- Q as QK B-operand fragments: B[n=query l15][k=d] (R7-verified)
    bf16x8 qf[2][2];                 // [qt2][ks]
    #pragma unroll
    for (int qt2 = 0; qt2 < 2; ++qt2) {
        const int qrow = qt * BQ + wave * 32 + qt2 * 16 + l15;
        const float* qsrc = Q + base + (size_t)(par + 2 * qrow) * D_ + quad * 8;
        #pragma unroll
        for (int ks = 0; ks < 2; ++ks) {
            const float4 a = *(const float4*)(qsrc + ks * 32);
            const float4 b = *(const float4*)(qsrc + ks * 32 + 4);
            bf16x8 w;
            w[0] = (__bf16)(a.x * QSCALE); w[1] = (__bf16)(a.y * QSCALE);
            w[2] = (__bf16)(a.z * QSCALE); w[3] = (__bf16)(a.w * QSCALE);
            w[4] = (__bf16)(b.x * QSCALE); w[5] = (__bf16)(b.y * QSCALE);
            w[6] = (__bf16)(b.z * QSCALE); w[7] = (__bf16)(b.w * QSCALE);
            qf[qt2][ks] = w;
        }
    }

    const __bf16* Kfb = Kf + (size_t)bp * NKT * 4096;   // 8 frags * 512 per kt
    const __bf16* Vfb = Vf + (size_t)bp * NKT * 4096;   // 16 frags * 256 per kt

    auto LOADK = [&](bf16x8* ka, int kt) {
        const __bf16* p = Kfb + (size_t)kt * 4096 + lane * 8;
        #pragma unroll
        for (int f = 0; f < 8; ++f) ka[f] = *(const bf16x8*)(p + f * 512);
    };
    auto LOADV = [&](bf16x4* va, int kt) {
        const __bf16* p = Vfb + (size_t)kt * 4096 + lane * 4;
        #pragma unroll
        for (int g = 0; g < 16; ++g) va[g] = *(const bf16x4*)(p + g * 256);
    };

    // O^T accumulators: C[m=d=quad*4+r (+16dt)][n=query=l15], per qt2
    f32x4 acc[2][4];
    #pragma unroll
    for (int q2 = 0; q2 < 2; ++q2)
        #pragma unroll
        for (int dt = 0; dt < 4; ++dt) acc[q2][dt] = (f32x4){0.f, 0.f, 0.f, 0.f};
    float l_acc[2] = {0.f, 0.f};

    auto COMPUTE = [&](const bf16x8* ka, const bf16x4* va) {
        #pragma unroll
        for (int qt2 = 0; qt2 < 2; ++qt2) {
            f32x4 st[4];
            #pragma unroll
            for (int kt4 = 0; kt4 < 4; ++kt4) st[kt4] = (f32x4){0.f, 0.f, 0.f, 0.f};
            #pragma unroll
            for (int ks = 0; ks < 2; ++ks)
                #pragma unroll
                for (int kt4 = 0; kt4 < 4; ++kt4)
                    st[kt4] = __builtin_amdgcn_mfma_f32_16x16x32_bf16(
                        ka[ks * 4 + kt4], qf[qt2][ks], st[kt4], 0, 0, 0);
            #pragma unroll
            for (int kt4 = 0; kt4 < 4; ++kt4) {
                const float p0 = EXP2(st[kt4][0]);
                const float p1 = EXP2(st[kt4][1]);
                const float p2 = EXP2(st[kt4][2]);
                const float p3 = EXP2(st[kt4][3]);
                l_acc[qt2] += (p0 + p1) + (p2 + p3);
                bf16x4 pb;
                pb[0] = (__bf16)p0; pb[1] = (__bf16)p1;
                pb[2] = (__bf16)p2; pb[3] = (__bf16)p3;
                #pragma unroll
                for (int dt = 0; dt < 4; ++dt)
                    acc[qt2][dt] = mfma16(va[kt4 * 4 + dt], pb, acc[qt2][dt]);
            }
        }
    };

    // ---- main loop: 2-deep register double-buffer, static A/B sets,
    // no LDS, no barriers; waves free-run.
    bf16x8 kaA[8], kaB[8];
    bf16x4 vaA[16], vaB[16];
    LOADK(kaA, 0); LOADV(vaA, 0);
    for (int kt = 0; kt < NKT; kt += 2) {
        LOADK(kaB, kt + 1); LOADV(vaB, kt + 1);   // NKT even: kt+1 <= 15
        COMPUTE(kaA, vaA);
        if (kt + 2 < NKT) { LOADK(kaA, kt + 2); LOADV(vaA, kt + 2); }
        COMPUTE(kaB, vaB);
    }

    // ---- epilogue: Z per query (fold quads), opp-parity Vsum from vpp
    float rz[2];
    #pragma unroll
    for (int qt2 = 0; qt2 < 2; ++qt2) {
        float Z = l_acc[qt2];
        Z += __shfl_xor(Z, 16);
        Z += __shfl_xor(Z, 32);
        rz[qt2] = 1.0f / (Z + 1024.0f);
    }
    const float* vsb = vpp + (size_t)(bh * 2 + (1 - par)) * NKT * 64;
    f32x4 vs4[4];
    #pragma unroll
    for (int dt = 0; dt < 4; ++dt) {
        f32x4 s = (f32x4){0.f, 0.f, 0.f, 0.f};
        #pragma unroll
        for (int kt = 0; kt < NKT; ++kt)
            s += *(const f32x4*)&vsb[kt * 64 + dt * 16 + quad * 4];
        vs4[dt] = s;
    }

    // ---- epilogue transpose: per-wave private f32 tile [16 q][68 d]
    __shared__ __align__(16) float tw_all[4][16 * 68];
    float* tw = tw_all[wave];
    #pragma unroll
    for (int qt2 = 0; qt2 < 2; ++qt2) {
        #pragma unroll
        for (int dt = 0; dt < 4; ++dt) {
            const f32x4 o = (acc[qt2][dt] + vs4[dt]) * rz[qt2];
            *(f32x4*)&tw[l15 * 68 + dt * 16 + quad * 4] = o;
        }
        // per-wave private + in-order DS pipe: no barrier needed
        #pragma unroll
        for (int i = 0; i < 4; ++i) {
            const int q = i * 4 + quad;
            const f32x4 ov = *(const f32x4*)&tw[q * 68 + l15 * 4];
            const int qg = par + 2 * (qt * BQ + wave * 32 + qt2 * 16 + q);
            *(f32x4*)&out[base + (size_t)qg * D_ + l15 * 4] = ov;
        }
    }
}

// ---------------------------------------------------------------------------
// Fallback path (verified R9): used only if ws_size is too small.
// ---------------------------------------------------------------------------
__global__ __launch_bounds__(1024) void vsum_kernel(const float* __restrict__ V,
                                                    float* __restrict__ vs) {
    const int bp  = blockIdx.x;
    const int bh  = bp >> 1;
    const int par = bp & 1;
    const int d   = threadIdx.x & 63;
    const int rg  = threadIdx.x >> 6;
    const float* Vb = V + (size_t)bh * S_ * D_;
    float s = 0.f;
    for (int r = rg; r < SP_; r += 16)
        s += Vb[(size_t)(par + 2 * r) * D_ + d];
    __shared__ float red[16][64];
    red[rg][d] = s;
    __syncthreads();
    if (rg == 0) {
        float t = 0.f;
        #pragma unroll
        for (int i = 0; i < 16; ++i) t += red[i][d];
        vs[(size_t)bp * 64 + d] = t;
    }
}

__global__ __launch_bounds__(256, 4) void attn_fb_kernel(const float* __restrict__ Q,
                                                         const float* __restrict__ K,
                                                         const float* __restrict__ V,
                                                         const float* __restrict__ vs,
                                                         float* __restrict__ out) {
    const int bh  = blockIdx.x;
    const int par = blockIdx.y;
    const int qt  = blockIdx.z;
    const int tid  = threadIdx.x;
    const int lane = tid & 63;
    const int wave = tid >> 6;
    const int l15  = lane & 15;
    const int quad = lane >> 4;

    __shared__ __align__(16) char arena[32768];
    __bf16 (*kbuf)[BK][64] = (__bf16 (*)[BK][64])arena;
    __bf16 (*vbuf)[D_][64] = (__bf16 (*)[D_][64])(arena + 16384);

    const size_t base = (size_t)bh * S_ * D_;
    const float* Qb = Q + base;
    const float* Kb = K + base;
    const float* Vb = V + base;

    bf16x8 qf[2];
    {
        const int qrow = qt * FBQ + wave * 16 + l15;
        const float* qsrc = Qb + (size_t)(par + 2 * qrow) * D_ + quad * 8;
        #pragma unroll
        for (int ks = 0; ks < 2; ++ks) {
            const float4 a = *(const float4*)(qsrc + ks * 32);
            const float4 b = *(const float4*)(qsrc + ks * 32 + 4);
            bf16x8 w;
            w[0] = (__bf16)(a.x * QSCALE); w[1] = (__bf16)(a.y * QSCALE);
            w[2] = (__bf16)(a.z * QSCALE); w[3] = (__bf16)(a.w * QSCALE);
            w[4] = (__bf16)(b.x * QSCALE); w[5] = (__bf16)(b.y * QSCALE);
            w[6] = (__bf16)(b.z * QSCALE); w[7] = (__bf16)(b.w * QSCALE);
            qf[ks] = w;
        }
    }

    const int kr0 = tid >> 3;
    const int kc8 = tid & 7;
    float4 pka[2], pkb[2];
    float  pv[16];

    auto issue_loads = [&](int kt) {
        #pragma unroll
        for (int i = 0; i < 2; ++i) {
            const int r = i * 32 + kr0;
            const float* ksrc = Kb + (size_t)(par + 2 * (kt * BK + r)) * D_ + kc8 * 8;
            pka[i] = *(const float4*)ksrc;
            pkb[i] = *(const float4*)(ksrc + 4);
        }
        #pragma unroll
        for (int i = 0; i < 2; ++i) {
            const int c = wave + 4 * i;
            const float* vsrc = Vb + (size_t)(par + 2 * (kt * BK + c * 8)) * D_ + lane;
            #pragma unroll
            for (int j = 0; j < 8; ++j)
                pv[i * 8 + j] = vsrc[(size_t)(2 * j) * D_];
        }
    };
    auto stage = [&](int buf) {
        #pragma unroll
        for (int i = 0; i < 2; ++i) {
            const int r = i * 32 + kr0;
            bf16x8 w;
            w[0] = (__bf16)pka[i].x; w[1] = (__bf16)pka[i].y;
            w[2] = (__bf16)pka[i].z; w[3] = (__bf16)pka[i].w;
            w[4] = (__bf16)pkb[i].x; w[5] = (__bf16)pkb[i].y;
            w[6] = (__bf16)pkb[i].z; w[7] = (__bf16)pkb[i].w;
            *(bf16x8*)&kbuf[buf][r][KSW(r, kc8)] = w;
        }
        #pragma unroll
        for (int i = 0; i < 2; ++i) {
            const int c = wave + 4 * i;
            bf16x8 w;
            #pragma unroll
            for (int j = 0; j < 8; ++j) w[j] = (__bf16)pv[i * 8 + j];
            *(bf16x8*)&vbuf[buf][lane][KSW(lane, c)] = w;
        }
    };

    issue_loads(0);
    stage(0);
    __syncthreads();

    f32x4 acc[4];
    #pragma unroll
    for (int dt = 0; dt < 4; ++dt) acc[dt] = (f32x4){0.f, 0.f, 0.f, 0.f};
    float l_acc = 0.f;

    for (int kt = 0; kt < NKT; ++kt) {
        const int cur = kt & 1;
        const bool pf = (kt + 1 < NKT);
        if (pf) issue_loads(kt + 1);

        const __bf16 (*kb)[64] = kbuf[cur];
        const __bf16 (*vb)[64] = vbuf[cur];

        bf16x8 ka[2][4];
        #pragma unroll
        for (int ks = 0; ks < 2; ++ks)
            #pragma unroll
            for (int kt4 = 0; kt4 < 4; ++kt4) {
                const int R = kt4 * 16 + l15;
                ka[ks][kt4] = *(const bf16x8*)&kb[R][KSW(R, ks * 4 + quad)];
            }
        bf16x4 va[4][4];
        #pragma unroll
        for (int dt = 0; dt < 4; ++dt) {
            const int R = dt * 16 + l15;
            const int ro = R & 7;
            #pragma unroll
            for (int kt4 = 0; kt4 < 4; ++kt4) {
                const int ch = (kt4 * 2 + (quad >> 1)) ^ ro;
                va[kt4][dt] = *(const bf16x4*)&vb[R][ch * 8 + (quad & 1) * 4];
            }
        }

        f32x4 st[4];
        #pragma unroll
        for (int kt4 = 0; kt4 < 4; ++kt4) st[kt4] = (f32x4){0.f, 0.f, 0.f, 0.f};
        #pragma unroll
        for (int ks = 0; ks < 2; ++ks)
            #pragma unroll
            for (int kt4 = 0; kt4 < 4; ++kt4)
                st[kt4] = __builtin_amdgcn_mfma_f32_16x16x32_bf16(
                    ka[ks][kt4], qf[ks], st[kt4], 0, 0, 0);
        #pragma unroll
        for (int kt4 = 0; kt4 < 4; ++kt4) {
            const float p0 = EXP2(st[kt4][0]);
            const float p1 = EXP2(st[kt4][1]);
            const float p2 = EXP2(st[kt4][2]);
            const float p3 = EXP2(st[kt4][3]);
            l_acc += (p0 + p1) + (p2 + p3);
            bf16x4 pb;
            pb[0] = (__bf16)p0; pb[1] = (__bf16)p1;
            pb[2] = (__bf16)p2; pb[3] = (__bf16)p3;
            #pragma unroll
            for (int dt = 0; dt < 4; ++dt)
                acc[dt] = mfma16(va[kt4][dt], pb, acc[dt]);
        }

        if (pf) stage(1 - cur);
        __syncthreads();
    }

    float Z = l_acc;
    Z += __shfl_xor(Z, 16);
    Z += __shfl_xor(Z, 32);
    const float rz = 1.0f / (Z + 1024.0f);
    const float* vso = vs + ((size_t)(bh * 2 + (1 - par))) * 64;

    float* tw = (float*)arena + wave * (16 * 68);
    #pragma unroll
    for (int dt = 0; dt < 4; ++dt) {
        const f32x4 vs4 = *(const f32x4*)&vso[dt * 16 + quad * 4];
        const f32x4 o = (acc[dt] + vs4) * rz;
        *(f32x4*)&tw[l15 * 68 + dt * 16 + quad * 4] = o;
    }
    #pragma unroll
    for (int i = 0; i < 4; ++i) {
        const int q = i * 4 + quad;
        const f32x4 ov = *(const f32x4*)&tw[q * 68 + l15 * 4];
        const int qg = par + 2 * (qt * FBQ + wave * 16 + q);
        *(f32x4*)&out[base + (size_t)qg * D_ + l15 * 4] = ov;
    }
}

extern "C" void kernel_launch(void* const* d_in, const int* in_sizes, int n_in,
                              void* d_out, int out_size, void* d_ws, size_t ws_size,
                              hipStream_t stream) {
    const float* Q = (const float*)d_in[0];
    const float* K = (const float*)d_in[1];
    const float* V = (const float*)d_in[2];
    float* out = (float*)d_out;

    const size_t KF_BYTES  = (size_t)64 * NKT * 4096 * sizeof(__bf16);  // 8 MB
    const size_t VF_BYTES  = (size_t)64 * NKT * 4096 * sizeof(__bf16);  // 8 MB
    const size_t VPP_BYTES = (size_t)64 * NKT * 64 * sizeof(float);     // 256 KB
    const size_t need = KF_BYTES + VF_BYTES + VPP_BYTES;

    if (ws_size >= need) {
        __bf16* Kf  = (__bf16*)d_ws;
        __bf16* Vf  = (__bf16*)((char*)d_ws + KF_BYTES);
        float*  vpp = (float*)((char*)d_ws + KF_BYTES + VF_BYTES);
        convf_kernel<<<dim3(64, NKT), dim3(256), 0, stream>>>(K, V, Kf, Vf, vpp);
        attn4_kernel<<<dim3(512), dim3(256), 0, stream>>>(Q, Kf, Vf, vpp, out);
    } else {
        float* vsn = (float*)d_ws;     // 16 KB (proven available in R9)
        vsum_kernel<<<dim3(B_ * H_ * 2), dim3(1024), 0, stream>>>(V, vsn);
        attn_fb_kernel<<<dim3(B_ * H_, 2, SP_ / FBQ), dim3(256), 0, stream>>>(
            Q, K, V, vsn, out);
    }
}